// Round 1
// baseline (161.196 us; speedup 1.0000x reference)
//
#include <hip/hip_runtime.h>

// Problem: B=1024, S=256, D=128, F=4D=512, H1=256, H2=64.
// Folding: feat@W1 = q@(W1a+W1c) [per-b bias] + k@(W1b-W1c) + (q*k)@W1d
//   => layer1 = [S x 256] @ [256 x 256] GEMM per batch (K = [k | q*k]).

typedef unsigned short u16;
typedef short bf16x8 __attribute__((ext_vector_type(8)));
typedef float f32x4 __attribute__((ext_vector_type(4)));

#define NBATCH 1024
#define SLEN 256
#define DD 128
#define NH1 256
#define NH2 64

// ws layout (bytes)
#define WS_WCATT 0         // [256][256] bf16 = 131072 B   (W1cat transposed: [n][k])
#define WS_W2T   131072    // [64][256]  bf16 = 32768 B    (W2 transposed: [o][h])
#define WS_WDS   163840    // 65 f32 (Wd[64], bd)
#define WS_BIAS1 164096    // [1024][256] f32 = 1 MB
#define WS_NEED  (164096 + 1048576)

__device__ __forceinline__ u16 f2bf(float f){
  union { float f; unsigned u; } v; v.f = f;
  unsigned r = v.u + 0x7fffu + ((v.u >> 16) & 1u);   // RNE
  return (u16)(r >> 16);
}
__device__ __forceinline__ int swz(int byte){        // row stride 512B XOR swizzle (16B grain)
  return byte ^ (((byte >> 9) & 7) << 4);
}
__device__ __forceinline__ float sigmoidf(float x){ return 1.f / (1.f + __expf(-x)); }

// ---- prep 1: fold weights to bf16, transposed ----
__global__ void prep_weights(const float* __restrict__ W1, const float* __restrict__ W2,
                             const float* __restrict__ Wd, const float* __restrict__ bd,
                             u16* __restrict__ WcatT, u16* __restrict__ W2T,
                             float* __restrict__ WdS){
  int n = blockIdx.x;      // hidden col 0..255
  int k = threadIdx.x;     // feat k 0..255
  float v;
  if (k < 128) v = W1[(128 + k) * NH1 + n] - W1[(256 + k) * NH1 + n];  // (B - C) for keys
  else         v = W1[(384 + (k - 128)) * NH1 + n];                    // D for q*k
  WcatT[n * 256 + k] = f2bf(v);
  if (n < NH2) W2T[n * 256 + k] = f2bf(W2[k * NH2 + n]);
  if (n == 0 && k < NH2) WdS[k] = Wd[k];
  if (n == 0 && k == NH2) WdS[NH2] = bd[0];
}

// ---- prep 2: per-batch layer1 bias = b1 + q @ (W1a + W1c) ----
__global__ void prep_bias(const float* __restrict__ q, const float* __restrict__ W1,
                          const float* __restrict__ b1, float* __restrict__ bias1){
  int b = blockIdx.x, j = threadIdx.x;
  const float* qb = q + b * DD;
  float acc = b1[j];
  #pragma unroll 8
  for (int d = 0; d < DD; ++d)
    acc += qb[d] * (W1[d * NH1 + j] + W1[(256 + d) * NH1 + j]);
  bias1[b * NH1 + j] = acc;
}

// ---- main: one block per batch ----
__global__ __launch_bounds__(256, 2)
void seqatt_main(const float* __restrict__ queries, const float* __restrict__ keys,
                 const int* __restrict__ keys_length,
                 const u16* __restrict__ WcatT, const u16* __restrict__ W2Tg,
                 const float* __restrict__ WdS, const float* __restrict__ bias1g,
                 const float* __restrict__ b2g, float* __restrict__ out)
{
  // LDS arena:
  //   0      A tile [32][256] bf16 (16K, swz)     \ overlapped by red [4][32][64] f32 (32K)
  //   16384  h1     [32][256] bf16 (16K, swz)     /
  //   32768  W2T    [64][256] bf16 (32K, swz)
  //   65536  scores f32[256]; 66560 q f32[128]; 67072 bias1 f32[256];
  //   68096  b2 f32[64]; 68352 Wd+bd f32[65]; 68608 red4 f32[8]
  __shared__ alignas(16) char smem[68640];
  float* red    = (float*)smem;
  float* scores = (float*)(smem + 65536);
  float* qs     = (float*)(smem + 66560);
  float* bias1s = (float*)(smem + 67072);
  float* b2s    = (float*)(smem + 68096);
  float* wds    = (float*)(smem + 68352);
  float* red4   = (float*)(smem + 68608);

  const int b = blockIdx.x;
  const int tid = threadIdx.x;
  const int lane = tid & 63;
  const int wave = tid >> 6;
  const int l15 = lane & 15;
  const int l4  = lane >> 4;
  const int nbase = wave * 64;

  if (tid < 128) qs[tid] = queries[b * DD + tid];
  bias1s[tid] = bias1g[b * NH1 + tid];
  if (tid < 64) b2s[tid] = b2g[tid];
  if (tid < 65) wds[tid] = WdS[tid];
  const int klen = keys_length[b];

  // stage W2T to LDS (swizzled), 2048 x 16B chunks
  #pragma unroll
  for (int c = 0; c < 8; ++c){
    int byte = (c * 256 + tid) * 16;
    uint4 v = *reinterpret_cast<const uint4*>(reinterpret_cast<const char*>(W2Tg) + byte);
    *reinterpret_cast<uint4*>(smem + swz(32768 + byte)) = v;
  }

  // wave-stationary B fragments of layer-1 weight (n-chunk = wave*64, full K=256)
  bf16x8 bfrag[4][8];
  #pragma unroll
  for (int nt = 0; nt < 4; ++nt){
    #pragma unroll
    for (int ks = 0; ks < 8; ++ks){
      int n = nbase + nt * 16 + l15;
      int k = ks * 32 + (l4 << 3);
      bfrag[nt][ks] = *reinterpret_cast<const bf16x8*>(WcatT + n * 256 + k);
    }
  }
  __syncthreads();

  const f32x4 fz = {0.f, 0.f, 0.f, 0.f};

  for (int st = 0; st < 8; ++st){
    const int s0 = st * 32;

    // ---- build A tile: rows = 32 positions, cols = [k bf16 | q*k bf16] ----
    {
      int r = tid >> 3, seg = tid & 7;   // 8 threads/row, 16 floats each
      const float* kp = keys + ((long)b * SLEN + (s0 + r)) * DD + seg * 16;
      float kv[16];
      #pragma unroll
      for (int i = 0; i < 16; i += 4){
        float4 f4 = *reinterpret_cast<const float4*>(kp + i);
        kv[i] = f4.x; kv[i+1] = f4.y; kv[i+2] = f4.z; kv[i+3] = f4.w;
      }
      u16 kb[16], qkb[16];
      #pragma unroll
      for (int i = 0; i < 16; ++i){
        kb[i]  = f2bf(kv[i]);
        qkb[i] = f2bf(kv[i] * qs[seg * 16 + i]);
      }
      int rowbyte = r * 512;
      union { u16 s[8]; uint4 v; } pk;
      #pragma unroll
      for (int h = 0; h < 2; ++h){
        #pragma unroll
        for (int i = 0; i < 8; ++i) pk.s[i] = kb[h * 8 + i];
        *reinterpret_cast<uint4*>(smem + swz(rowbyte + seg * 32 + h * 16)) = pk.v;
      }
      #pragma unroll
      for (int h = 0; h < 2; ++h){
        #pragma unroll
        for (int i = 0; i < 8; ++i) pk.s[i] = qkb[h * 8 + i];
        *reinterpret_cast<uint4*>(smem + swz(rowbyte + 256 + seg * 32 + h * 16)) = pk.v;
      }
    }
    __syncthreads();

    // ---- GEMM1: h1_pre = A @ W1cat (per wave: M=32, N=64, K=256) ----
    f32x4 acc[2][4];
    #pragma unroll
    for (int mt = 0; mt < 2; ++mt)
      #pragma unroll
      for (int nt = 0; nt < 4; ++nt) acc[mt][nt] = fz;
    #pragma unroll
    for (int ks = 0; ks < 8; ++ks){
      bf16x8 af[2];
      #pragma unroll
      for (int mt = 0; mt < 2; ++mt){
        int byte = (mt * 16 + l15) * 512 + (ks * 32 + (l4 << 3)) * 2;
        af[mt] = *reinterpret_cast<const bf16x8*>(smem + swz(byte));
      }
      #pragma unroll
      for (int mt = 0; mt < 2; ++mt)
        #pragma unroll
        for (int nt = 0; nt < 4; ++nt)
          acc[mt][nt] = __builtin_amdgcn_mfma_f32_16x16x32_bf16(af[mt], bfrag[nt][ks], acc[mt][nt], 0, 0, 0);
    }

    // ---- bias + sigmoid -> h1 LDS bf16 (wave writes its own n-columns) ----
    #pragma unroll
    for (int mt = 0; mt < 2; ++mt)
      #pragma unroll
      for (int nt = 0; nt < 4; ++nt){
        int col = nbase + nt * 16 + l15;
        float bia = bias1s[col];
        #pragma unroll
        for (int i = 0; i < 4; ++i){
          int row = mt * 16 + (l4 << 2) + i;
          float h = sigmoidf(acc[mt][nt][i] + bia);
          *reinterpret_cast<u16*>(smem + swz(16384 + row * 512 + col * 2)) = f2bf(h);
        }
      }
    // no barrier: each wave reads back only the h1 columns it wrote (k-split below)

    // ---- GEMM2: h2_pre partial over this wave's K-quarter ----
    f32x4 acc2[2][4];
    #pragma unroll
    for (int mt = 0; mt < 2; ++mt)
      #pragma unroll
      for (int nt = 0; nt < 4; ++nt) acc2[mt][nt] = fz;
    #pragma unroll
    for (int ks2 = 0; ks2 < 2; ++ks2){
      int kk = wave * 64 + ks2 * 32 + (l4 << 3);
      bf16x8 a2[2], b2f[4];
      #pragma unroll
      for (int mt = 0; mt < 2; ++mt){
        int byte = 16384 + (mt * 16 + l15) * 512 + kk * 2;
        a2[mt] = *reinterpret_cast<const bf16x8*>(smem + swz(byte));
      }
      #pragma unroll
      for (int nt = 0; nt < 4; ++nt){
        int byte = 32768 + (nt * 16 + l15) * 512 + kk * 2;
        b2f[nt] = *reinterpret_cast<const bf16x8*>(smem + swz(byte));
      }
      #pragma unroll
      for (int mt = 0; mt < 2; ++mt)
        #pragma unroll
        for (int nt = 0; nt < 4; ++nt)
          acc2[mt][nt] = __builtin_amdgcn_mfma_f32_16x16x32_bf16(a2[mt], b2f[nt], acc2[mt][nt], 0, 0, 0);
    }
    __syncthreads();   // all h1/A reads done before red overwrites bytes [0,32768)

    {
      float* rw = red + wave * 2048;   // [32][64] f32 partial
      #pragma unroll
      for (int mt = 0; mt < 2; ++mt)
        #pragma unroll
        for (int nt = 0; nt < 4; ++nt)
          #pragma unroll
          for (int i = 0; i < 4; ++i){
            int r = mt * 16 + (l4 << 2) + i;
            int o = nt * 16 + l15;
            rw[r * 64 + o] = acc2[mt][nt][i];
          }
    }
    __syncthreads();

    // ---- reduce 4 partials, bias2, sigmoid, dot with Wd -> score ----
    {
      int r = tid >> 3, g = tid & 7;
      float p = 0.f;
      #pragma unroll
      for (int oo = 0; oo < 8; ++oo){
        int o = g * 8 + oo;
        float v = red[r * 64 + o] + red[2048 + r * 64 + o] +
                  red[4096 + r * 64 + o] + red[6144 + r * 64 + o];
        float h = sigmoidf(v + b2s[o]);
        p += h * wds[o];
      }
      p += __shfl_xor(p, 1);
      p += __shfl_xor(p, 2);
      p += __shfl_xor(p, 4);
      if (g == 0){
        int s = s0 + r;
        float sc = (p + wds[64]) * 0.08838834764831845f;   // 1/sqrt(128)
        scores[s] = (s < klen) ? sc : -1e30f;              // mask fill
      }
    }
    __syncthreads();
  }

  // ---- softmax over S=256 ----
  {
    float v = scores[tid];
    float m = v;
    #pragma unroll
    for (int off = 32; off >= 1; off >>= 1) m = fmaxf(m, __shfl_xor(m, off));
    if (lane == 0) red4[wave] = m;
    __syncthreads();
    float mx = fmaxf(fmaxf(red4[0], red4[1]), fmaxf(red4[2], red4[3]));
    float e = __expf(v - mx);
    float ssum = e;
    #pragma unroll
    for (int off = 32; off >= 1; off >>= 1) ssum += __shfl_xor(ssum, off);
    if (lane == 0) red4[4 + wave] = ssum;
    __syncthreads();
    float tot = red4[4] + red4[5] + red4[6] + red4[7];
    scores[tid] = e / tot;
    __syncthreads();
  }

  // ---- out[b][d] = sum_s w[s] * keys[b][s][d]  (fp32) ----
  {
    int d = tid & 127, half = tid >> 7;
    const float* kb = keys + ((long)b * SLEN + half * 128) * DD + d;
    float acc = 0.f;
    #pragma unroll 4
    for (int s2 = 0; s2 < 128; ++s2) acc += scores[half * 128 + s2] * kb[s2 * DD];
    red[tid] = acc;
    __syncthreads();
    if (tid < 128) out[b * DD + tid] = red[tid] + red[128 + tid];
  }
}

extern "C" void kernel_launch(void* const* d_in, const int* in_sizes, int n_in,
                              void* d_out, int out_size, void* d_ws, size_t ws_size,
                              hipStream_t stream) {
  const float* queries     = (const float*)d_in[0];
  const float* keys        = (const float*)d_in[1];
  const int*   keys_length = (const int*)d_in[2];
  const float* W1 = (const float*)d_in[3];
  const float* b1 = (const float*)d_in[4];
  const float* W2 = (const float*)d_in[5];
  const float* b2 = (const float*)d_in[6];
  const float* Wd = (const float*)d_in[7];
  const float* bd = (const float*)d_in[8];
  float* out = (float*)d_out;
  char* ws = (char*)d_ws;

  u16*   WcatT = (u16*)(ws + WS_WCATT);
  u16*   W2T   = (u16*)(ws + WS_W2T);
  float* WdS   = (float*)(ws + WS_WDS);
  float* bias1 = (float*)(ws + WS_BIAS1);

  prep_weights<<<dim3(256), dim3(256), 0, stream>>>(W1, W2, Wd, bd, WcatT, W2T, WdS);
  prep_bias<<<dim3(NBATCH), dim3(256), 0, stream>>>(queries, W1, b1, bias1);
  seqatt_main<<<dim3(NBATCH), dim3(256), 0, stream>>>(queries, keys, keys_length,
                                                      WcatT, W2T, WdS, bias1, b2, out);
}